// Round 2
// baseline (17026.819 us; speedup 1.0000x reference)
//
#include <hip/hip_runtime.h>
#include <hip/hip_bf16.h>

#define DEV __device__ __forceinline__

typedef __bf16 bf16;
typedef __bf16 bf16x8 __attribute__((ext_vector_type(8)));
typedef float f32x4 __attribute__((ext_vector_type(4)));
typedef unsigned int u32;

// problem constants
#define BB 32
#define TT 512
#define DIN 1024
#define HH 512
#define G4 2048          // 4H
#define MM (TT*BB)       // 16384 rows (t-major: r = t*32 + b)

DEV float sigmf(float x){ return 1.0f/(1.0f + __expf(-x)); }
DEV float tanhfast(float x){ return 1.0f - 2.0f/(__expf(2.0f*x)+1.0f); }

DEV void gload16(const void* g, void* l){
  __builtin_amdgcn_global_load_lds((const __attribute__((address_space(1))) void*)g,
                                   (__attribute__((address_space(3))) void*)l, 16, 0, 0);
}

// ---------------- debug: report ws_size via absmax ----------------
__global__ void k_dbg(float* out, float v){ out[0] = v; }

// ---------------- prep: bias sum + counter zero ----------------
__global__ void k_prep_bias(const float* __restrict__ bx, const float* __restrict__ bh,
                            float* __restrict__ bsum, u32* __restrict__ ctr){
  int gid = blockIdx.x*256 + threadIdx.x;
  if (gid < 4*G4) bsum[gid] = bx[gid] + bh[gid];
  if (gid < 8) ctr[gid] = 0;
}

// ---------------- x -> bf16, row r = t*32+b, XOR-swizzled 16B chunks ----------------
__global__ void k_xswz(const float* __restrict__ x, bf16* __restrict__ xs){
  int gid = blockIdx.x*256 + threadIdx.x;   // 16384*128
  int r = gid >> 7, kc = gid & 127;
  int b = r & 31, t = r >> 5;
  const float* px = x + ((size_t)b*TT + t)*DIN + kc*8;
  float4 v0 = *(const float4*)px;
  float4 v1 = *(const float4*)(px+4);
  bf16x8 o;
  o[0]=(bf16)v0.x; o[1]=(bf16)v0.y; o[2]=(bf16)v0.z; o[3]=(bf16)v0.w;
  o[4]=(bf16)v1.x; o[5]=(bf16)v1.y; o[6]=(bf16)v1.z; o[7]=(bf16)v1.w;
  *(bf16x8*)(xs + (size_t)r*DIN + ((kc ^ (r&7))<<3)) = o;
}

// ---------------- Wx: [ld][k=1024][n=2048] f32 -> [ld][n][k] bf16, swizzled ----------------
__global__ void k_twx(const float* __restrict__ Wx, bf16* __restrict__ Wxt){
  int ld = blockIdx.z;
  int k0 = blockIdx.x*64, n0 = blockIdx.y*64;
  const float* in = Wx + (size_t)ld*DIN*G4;
  bf16* outp = Wxt + (size_t)ld*G4*DIN;
  __shared__ float tile[64][68];
  int tid = threadIdx.x;
  #pragma unroll
  for (int rr=0; rr<4; rr++){
    int row = rr*16 + (tid>>4); int c4 = (tid&15)*4;
    float4 v = *(const float4*)(in + (size_t)(k0+row)*G4 + n0 + c4);
    *(float4*)&tile[row][c4] = v;
  }
  __syncthreads();
  #pragma unroll
  for (int uu=0; uu<2; uu++){
    int u = uu*256 + tid;
    int nn = u>>3, ck = u&7;
    bf16x8 o;
    #pragma unroll
    for (int j=0;j<8;j++) o[j] = (bf16)tile[ck*8+j][nn];
    int ncol = n0 + nn;
    int kcg = (k0>>3) + ck;
    *(bf16x8*)(outp + (size_t)ncol*DIN + ((size_t)(kcg ^ (ncol&7))<<3)) = o;
  }
}

// ---------------- Wh: [ld][k=512][n=2048] f32 -> [ld][cc][k] bf16 (col remap) ----------------
__global__ void k_twh(const float* __restrict__ Wh, bf16* __restrict__ Whb){
  int ld = blockIdx.z;
  int k0 = blockIdx.x*64, n0 = blockIdx.y*64;
  const float* in = Wh + (size_t)ld*HH*G4;
  bf16* outp = Whb + (size_t)ld*G4*HH;
  __shared__ float tile[64][68];
  int tid = threadIdx.x;
  #pragma unroll
  for (int rr=0; rr<4; rr++){
    int row = rr*16 + (tid>>4); int c4 = (tid&15)*4;
    float4 v = *(const float4*)(in + (size_t)(k0+row)*G4 + n0 + c4);
    *(float4*)&tile[row][c4] = v;
  }
  __syncthreads();
  #pragma unroll
  for (int uu=0; uu<2; uu++){
    int u = uu*256 + tid;
    int nn = u>>3, ck = u&7;
    bf16x8 o;
    #pragma unroll
    for (int j=0;j<8;j++) o[j] = (bf16)tile[ck*8+j][nn];
    int n = n0 + nn;
    int q = n >> 9, rem = n & 511;
    int s = rem >> 4, wq = (rem >> 2) & 3, hcv = rem & 3;
    int cc = s*64 + wq*16 + q*4 + hcv;   // gate-interleaved col order
    *(bf16x8*)(outp + (size_t)cc*HH + k0 + ck*8) = o;
  }
}

// ---------------- gx GEMM: [16384,1024]bf16 @ [1024,2048]bf16 -> GXT (+bias) ----------------
template<typename GXT>
__launch_bounds__(256, 1)
__global__ void k_gemm(const bf16* __restrict__ A, const bf16* __restrict__ Bw,
                       const float* __restrict__ bias, GXT* __restrict__ out){
  int d = blockIdx.z;
  const bf16* Bp = Bw + (size_t)d*G4*DIN;
  const float* bp = bias + d*G4;
  GXT* op = out + (size_t)d*MM*G4;
  int n0 = blockIdx.x*128, r0 = blockIdx.y*128;
  int tid = threadIdx.x, lane = tid&63, w = tid>>6;
  __shared__ __align__(16) bf16 ldsA[128*64];
  __shared__ __align__(16) bf16 ldsB[128*64];
  f32x4 acc[4][4];
  #pragma unroll
  for (int i=0;i<4;i++)
    #pragma unroll
    for (int j=0;j<4;j++) acc[i][j] = (f32x4){0.f,0.f,0.f,0.f};
  int wm = w>>1, wn = w&1;
  for (int kt=0; kt<16; kt++){
    __syncthreads();
    #pragma unroll
    for (int p=0;p<4;p++){
      int seg = p*4 + w;
      int row = seg*8 + (lane>>3);
      int cch = lane&7;
      gload16(A  + (size_t)(r0+row)*DIN + kt*64 + cch*8, ldsA + seg*512);
      gload16(Bp + (size_t)(n0+row)*DIN + kt*64 + cch*8, ldsB + seg*512);
    }
    __syncthreads();
    #pragma unroll
    for (int ks=0; ks<2; ks++){
      bf16x8 af[4], bf_[4];
      #pragma unroll
      for (int at=0; at<4; at++){
        int row = wm*64 + at*16 + (lane&15);
        int ch = (ks*4 + (lane>>4)) ^ (row&7);
        af[at] = *(const bf16x8*)(ldsA + row*64 + ch*8);
      }
      #pragma unroll
      for (int bt=0; bt<4; bt++){
        int col = wn*64 + bt*16 + (lane&15);
        int ch = (ks*4 + (lane>>4)) ^ (col&7);
        bf_[bt] = *(const bf16x8*)(ldsB + col*64 + ch*8);
      }
      #pragma unroll
      for (int at=0; at<4; at++)
        #pragma unroll
        for (int bt=0; bt<4; bt++)
          acc[at][bt] = __builtin_amdgcn_mfma_f32_16x16x32_bf16(af[at], bf_[bt], acc[at][bt], 0,0,0);
    }
  }
  float bv[4];
  #pragma unroll
  for (int bt=0;bt<4;bt++) bv[bt] = bp[n0 + wn*64 + bt*16 + (lane&15)];
  #pragma unroll
  for (int at=0; at<4; at++)
    #pragma unroll
    for (int bt=0; bt<4; bt++)
      #pragma unroll
      for (int rg=0; rg<4; rg++){
        int row = r0 + wm*64 + at*16 + (lane>>4)*4 + rg;
        int col = n0 + wn*64 + bt*16 + (lane&15);
        op[(size_t)row*G4 + col] = (GXT)(acc[at][bt][rg] + bv[bt]);
      }
}

// ---------------- recurrence: (32*ndirs) WGs = ndirs dirs x 32 col-slices ----------------
template<typename GXT>
__launch_bounds__(256, 1)
__global__ void k_rec(const bf16* __restrict__ Whb, const GXT* __restrict__ gx,
                      bf16* __restrict__ hbuf, u32* __restrict__ ctr,
                      bf16* __restrict__ out0, float* __restrict__ dout,
                      float* __restrict__ hn, float* __restrict__ cn, int layer, int dir0){
  int tid = threadIdx.x, lane = tid&63, w = tid>>6;
  int dl = blockIdx.x >> 5, s = blockIdx.x & 31;
  int d = dir0 + dl;                          // actual direction
  __shared__ __align__(16) bf16 hA[32*512];   // 32KB, XOR-swizzled
  __shared__ __align__(16) bf16 hOut[32*16];  // 1KB gather for coalesced writes
  const bf16* Wp = Whb + ((size_t)d*G4 + s*64 + w*16 + (lane&15))*HH;
  bf16x8 bfr[16];
  #pragma unroll
  for (int kk=0; kk<16; kk++) bfr[kk] = *(const bf16x8*)(Wp + kk*32 + (lane>>4)*8);
  float cst[2][4] = {{0,0,0,0},{0,0,0,0}};
  const GXT* gxD = gx + (size_t)dl*MM*G4;
  int q = (lane>>2)&3, hc = lane&3;
  int colg = q*HH + s*16 + w*4 + hc;
  int m0 = lane&15;
  bool hi = (q >= 2), odd = (q & 1);

  for (int t=0; t<TT; t++){
    int tt = d ? (TT-1-t) : t;
    if (t > 0){
      if (tid == 0){
        u32 tgt = (u32)(32*t);
        while (__hip_atomic_load(ctr + d, __ATOMIC_ACQUIRE, __HIP_MEMORY_SCOPE_AGENT) < tgt)
          __builtin_amdgcn_s_sleep(2);
      }
      __syncthreads();
      __threadfence();   // acquire: cross-XCD visibility of hbuf
    }
    // gx prefetch (overlaps staging + MFMA)
    float gxv[2][4];
    {
      const GXT* gp = gxD + (size_t)tt*BB*G4 + colg;
      #pragma unroll
      for (int mt=0; mt<2; mt++)
        #pragma unroll
        for (int rg=0; rg<4; rg++)
          gxv[mt][rg] = (float)gp[(size_t)(mt*16 + (lane>>4)*4 + rg)*G4];
    }
    f32x4 acc0 = {0.f,0.f,0.f,0.f}, acc1 = {0.f,0.f,0.f,0.f};
    if (t > 0){
      const bf16* hsrc = hbuf + ((size_t)d*2 + ((t-1)&1))*BB*HH;
      #pragma unroll
      for (int i=0;i<8;i++){
        int u = i*256 + tid;
        int b = u>>6, kc = u&63;
        bf16x8 v = *(const bf16x8*)(hsrc + b*HH + kc*8);
        *(bf16x8*)(hA + b*HH + ((kc ^ (b&7))<<3)) = v;
      }
      __syncthreads();
      #pragma unroll
      for (int kk=0; kk<16; kk++){
        int ch = (kk*4 + (lane>>4)) ^ (m0&7);
        bf16x8 a0 = *(const bf16x8*)(hA + m0*HH + ch*8);
        bf16x8 a1 = *(const bf16x8*)(hA + (m0+16)*HH + ch*8);
        acc0 = __builtin_amdgcn_mfma_f32_16x16x32_bf16(a0, bfr[kk], acc0, 0,0,0);
        acc1 = __builtin_amdgcn_mfma_f32_16x16x32_bf16(a1, bfr[kk], acc1, 0,0,0);
      }
    }
    // gates + cell update (gate exchange inside 16-lane groups via shfl_xor)
    #pragma unroll
    for (int mt=0; mt<2; mt++){
      #pragma unroll
      for (int rg=0; rg<4; rg++){
        float gpre = (mt ? acc1[rg] : acc0[rg]) + gxv[mt][rg];
        float x4  = __shfl_xor(gpre, 4);
        float x8  = __shfl_xor(gpre, 8);
        float x12 = __shfl_xor(gpre, 12);
        float a04 = odd ? x4 : gpre,  b04 = odd ? gpre : x4;
        float a812 = odd ? x12 : x8,  b812 = odd ? x8 : x12;
        float ig = hi ? a812 : a04;
        float fg = hi ? b812 : b04;
        float gg = hi ? a04 : a812;
        float og = hi ? b04 : b812;
        float iv = sigmf(ig), fv = sigmf(fg), gv = tanhfast(gg), ov = sigmf(og);
        float c = cst[mt][rg]*fv + iv*gv;
        cst[mt][rg] = c;
        float hvv = ov * tanhfast(c);
        if (q == 0){
          int b = mt*16 + (lane>>4)*4 + rg;
          hOut[b*16 + w*4 + hc] = (bf16)hvv;
          if (layer == 1)   // full-precision output write (skip bf16 roundtrip)
            dout[((size_t)(b*TT + tt))*(2*HH) + d*HH + s*16 + w*4 + hc] = hvv;
          if (t == TT-1)
            hn[((size_t)((layer*2+d)*BB + b))*HH + s*16 + w*4 + hc] = hvv;
        }
      }
    }
    __syncthreads();
    if (tid < 64){
      int b = tid>>1, half = tid&1;
      bf16x8 v = *(const bf16x8*)(hOut + b*16 + half*8);
      *(bf16x8*)(hbuf + ((size_t)d*2 + (t&1))*BB*HH + b*HH + s*16 + half*8) = v;
      if (layer == 0){
        int r = tt*BB + b;
        int chunk = (d*64 + s*2 + half) ^ (r&7);
        *(bf16x8*)(out0 + (size_t)r*DIN + chunk*8) = v;
      }
    }
    if (t == TT-1 && q == 0){
      #pragma unroll
      for (int mt=0; mt<2; mt++)
        #pragma unroll
        for (int rg=0; rg<4; rg++){
          int b = mt*16 + (lane>>4)*4 + rg;
          cn[((size_t)((layer*2+d)*BB + b))*HH + s*16 + w*4 + hc] = cst[mt][rg];
        }
    }
    __threadfence();    // release: h visible before counter bump
    __syncthreads();
    if (tid == 0)
      __hip_atomic_fetch_add(ctr + d, 1u, __ATOMIC_RELEASE, __HIP_MEMORY_SCOPE_AGENT);
  }
}

extern "C" void kernel_launch(void* const* d_in, const int* in_sizes, int n_in,
                              void* d_out, int out_size, void* d_ws, size_t ws_size,
                              hipStream_t stream){
  const float* x  = (const float*)d_in[0];
  const float* Wx = (const float*)d_in[1];
  const float* bx = (const float*)d_in[2];
  const float* Wh = (const float*)d_in[3];
  const float* bh = (const float*)d_in[4];
  float* outp = (float*)d_out;
  char* ws = (char*)d_ws;

  const size_t szWxt  = (size_t)4*G4*DIN*2;   // 16.8 MB
  const size_t szWhb  = (size_t)4*G4*HH*2;    // 8.4 MB
  const size_t szBsum = (size_t)4*G4*4;
  const size_t szXO   = (size_t)MM*DIN*2;     // 33.6 MB
  const size_t szHbuf = (size_t)2*2*BB*HH*2;
  const size_t szCtr  = 256;

  // mode 0: f32 gx, both dirs, xo/out0 shared        (~327 MB)
  // mode 1: bf16 gx, both dirs, xo/out0 shared       (~193 MB)
  // mode 2: bf16 gx, one dir, separate out0, serial  (~160 MB)
  int mode = -1;
  size_t oWxt=0,oWhb=0,oBsum=0,oXO=0,oOut0=0,oHbuf=0,oCtr=0,oGx=0;
  for (int m=0; m<3 && mode<0; m++){
    size_t off = 0;
    auto take = [&](size_t b)->size_t{ size_t r = off; off = (off + b + 255) & ~(size_t)255; return r; };
    oWxt = take(szWxt); oWhb = take(szWhb); oBsum = take(szBsum);
    oXO  = take(szXO);
    oOut0 = (m==2) ? take(szXO) : oXO;
    oHbuf = take(szHbuf); oCtr = take(szCtr);
    size_t gxb = (m==0) ? (size_t)2*MM*G4*4 : (m==1) ? (size_t)2*MM*G4*2 : (size_t)MM*G4*2;
    oGx = take(gxb);
    if (off <= ws_size) mode = m;
  }
  if (mode < 0){
    k_dbg<<<1, 1, 0, stream>>>(outp, (float)((double)ws_size / 1048576.0));
    return;
  }

  bf16* Wxt  = (bf16*)(ws + oWxt);
  bf16* Whb  = (bf16*)(ws + oWhb);
  float* bsum= (float*)(ws + oBsum);
  bf16* xo   = (bf16*)(ws + oXO);
  bf16* out0 = (bf16*)(ws + oOut0);
  bf16* hbuf = (bf16*)(ws + oHbuf);
  u32*  ctr  = (u32*)(ws + oCtr);
  void* gxp  = (void*)(ws + oGx);

  float* hn = outp + (size_t)BB*TT*2*HH;
  float* cn = hn + (size_t)4*BB*HH;

  k_prep_bias<<<32, 256, 0, stream>>>(bx, bh, bsum, ctr);
  k_xswz<<<(MM*128)/256, 256, 0, stream>>>(x, xo);
  k_twx<<<dim3(16,32,4), 256, 0, stream>>>(Wx, Wxt);
  k_twh<<<dim3(8,32,4), 256, 0, stream>>>(Wh, Whb);

  if (mode == 0){
    float* gx = (float*)gxp;
    for (int layer=0; layer<2; layer++){
      k_gemm<float><<<dim3(16,128,2), 256, 0, stream>>>(xo, Wxt + (size_t)layer*2*G4*DIN,
                                                        bsum + layer*2*G4, gx);
      k_rec<float><<<64, 256, 0, stream>>>(Whb + (size_t)layer*2*G4*HH, gx, hbuf,
                                           ctr + layer*2, out0, outp, hn, cn, layer, 0);
    }
  } else if (mode == 1){
    bf16* gx = (bf16*)gxp;
    for (int layer=0; layer<2; layer++){
      k_gemm<bf16><<<dim3(16,128,2), 256, 0, stream>>>(xo, Wxt + (size_t)layer*2*G4*DIN,
                                                       bsum + layer*2*G4, gx);
      k_rec<bf16><<<64, 256, 0, stream>>>(Whb + (size_t)layer*2*G4*HH, gx, hbuf,
                                          ctr + layer*2, out0, outp, hn, cn, layer, 0);
    }
  } else {
    bf16* gx = (bf16*)gxp;
    for (int layer=0; layer<2; layer++){
      const bf16* A = layer ? out0 : xo;
      for (int dd=0; dd<2; dd++){
        k_gemm<bf16><<<dim3(16,128,1), 256, 0, stream>>>(A, Wxt + (size_t)(layer*2+dd)*G4*DIN,
                                                         bsum + (layer*2+dd)*G4, gx);
        k_rec<bf16><<<32, 256, 0, stream>>>(Whb + (size_t)layer*2*G4*HH, gx, hbuf,
                                            ctr + layer*2, out0, outp, hn, cn, layer, dd);
      }
    }
  }
}

// Round 3
// 8572.888 us; speedup vs baseline: 1.9861x; 1.9861x over previous
//
#include <hip/hip_runtime.h>
#include <hip/hip_bf16.h>

#define DEV __device__ __forceinline__

typedef __bf16 bf16;
typedef __bf16 bf16x8 __attribute__((ext_vector_type(8)));
typedef float f32x4 __attribute__((ext_vector_type(4)));
typedef unsigned int u32;

// problem constants
#define BB 32
#define TT 512
#define DIN 1024
#define HH 512
#define G4 2048          // 4H
#define MM (TT*BB)       // 16384 rows (t-major: r = t*32 + b)

DEV float sigmf(float x){ return 1.0f/(1.0f + __expf(-x)); }
DEV float tanhfast(float x){ return 1.0f - 2.0f/(__expf(2.0f*x)+1.0f); }

DEV void gload16(const void* g, void* l){
  __builtin_amdgcn_global_load_lds((const __attribute__((address_space(1))) void*)g,
                                   (__attribute__((address_space(3))) void*)l, 16, 0, 0);
}

// ---------------- debug: report ws_size via absmax ----------------
__global__ void k_dbg(float* out, float v){ out[0] = v; }

// ---------------- prep: bias sum + counter zero ----------------
__global__ void k_prep_bias(const float* __restrict__ bx, const float* __restrict__ bh,
                            float* __restrict__ bsum, u32* __restrict__ ctr){
  int gid = blockIdx.x*256 + threadIdx.x;
  if (gid < 4*G4) bsum[gid] = bx[gid] + bh[gid];
  if (gid < 128) ctr[gid] = 0;   // [layer][dir][32]
}

// ---------------- x -> bf16, row r = t*32+b, XOR-swizzled 16B chunks ----------------
__global__ void k_xswz(const float* __restrict__ x, bf16* __restrict__ xs){
  int gid = blockIdx.x*256 + threadIdx.x;   // 16384*128
  int r = gid >> 7, kc = gid & 127;
  int b = r & 31, t = r >> 5;
  const float* px = x + ((size_t)b*TT + t)*DIN + kc*8;
  float4 v0 = *(const float4*)px;
  float4 v1 = *(const float4*)(px+4);
  bf16x8 o;
  o[0]=(bf16)v0.x; o[1]=(bf16)v0.y; o[2]=(bf16)v0.z; o[3]=(bf16)v0.w;
  o[4]=(bf16)v1.x; o[5]=(bf16)v1.y; o[6]=(bf16)v1.z; o[7]=(bf16)v1.w;
  *(bf16x8*)(xs + (size_t)r*DIN + ((kc ^ (r&7))<<3)) = o;
}

// ---------------- Wx: [ld][k=1024][n=2048] f32 -> [ld][n][k] bf16, swizzled ----------------
__global__ void k_twx(const float* __restrict__ Wx, bf16* __restrict__ Wxt){
  int ld = blockIdx.z;
  int k0 = blockIdx.x*64, n0 = blockIdx.y*64;
  const float* in = Wx + (size_t)ld*DIN*G4;
  bf16* outp = Wxt + (size_t)ld*G4*DIN;
  __shared__ float tile[64][68];
  int tid = threadIdx.x;
  #pragma unroll
  for (int rr=0; rr<4; rr++){
    int row = rr*16 + (tid>>4); int c4 = (tid&15)*4;
    float4 v = *(const float4*)(in + (size_t)(k0+row)*G4 + n0 + c4);
    *(float4*)&tile[row][c4] = v;
  }
  __syncthreads();
  #pragma unroll
  for (int uu=0; uu<2; uu++){
    int u = uu*256 + tid;
    int nn = u>>3, ck = u&7;
    bf16x8 o;
    #pragma unroll
    for (int j=0;j<8;j++) o[j] = (bf16)tile[ck*8+j][nn];
    int ncol = n0 + nn;
    int kcg = (k0>>3) + ck;
    *(bf16x8*)(outp + (size_t)ncol*DIN + ((size_t)(kcg ^ (ncol&7))<<3)) = o;
  }
}

// ---------------- Wh: [ld][k=512][n=2048] f32 -> [ld][cc][k] bf16 (col remap) ----------------
__global__ void k_twh(const float* __restrict__ Wh, bf16* __restrict__ Whb){
  int ld = blockIdx.z;
  int k0 = blockIdx.x*64, n0 = blockIdx.y*64;
  const float* in = Wh + (size_t)ld*HH*G4;
  bf16* outp = Whb + (size_t)ld*G4*HH;
  __shared__ float tile[64][68];
  int tid = threadIdx.x;
  #pragma unroll
  for (int rr=0; rr<4; rr++){
    int row = rr*16 + (tid>>4); int c4 = (tid&15)*4;
    float4 v = *(const float4*)(in + (size_t)(k0+row)*G4 + n0 + c4);
    *(float4*)&tile[row][c4] = v;
  }
  __syncthreads();
  #pragma unroll
  for (int uu=0; uu<2; uu++){
    int u = uu*256 + tid;
    int nn = u>>3, ck = u&7;
    bf16x8 o;
    #pragma unroll
    for (int j=0;j<8;j++) o[j] = (bf16)tile[ck*8+j][nn];
    int n = n0 + nn;
    int q = n >> 9, rem = n & 511;
    int s = rem >> 4, wq = (rem >> 2) & 3, hcv = rem & 3;
    int cc = s*64 + wq*16 + q*4 + hcv;   // gate-interleaved col order
    *(bf16x8*)(outp + (size_t)cc*HH + k0 + ck*8) = o;
  }
}

// ---------------- gx GEMM: [16384,1024]bf16 @ [1024,2048]bf16 -> GXT (+bias) ----------------
template<typename GXT>
__launch_bounds__(256, 1)
__global__ void k_gemm(const bf16* __restrict__ A, const bf16* __restrict__ Bw,
                       const float* __restrict__ bias, GXT* __restrict__ out){
  int d = blockIdx.z;
  const bf16* Bp = Bw + (size_t)d*G4*DIN;
  const float* bp = bias + d*G4;
  GXT* op = out + (size_t)d*MM*G4;
  int n0 = blockIdx.x*128, r0 = blockIdx.y*128;
  int tid = threadIdx.x, lane = tid&63, w = tid>>6;
  __shared__ __align__(16) bf16 ldsA[128*64];
  __shared__ __align__(16) bf16 ldsB[128*64];
  f32x4 acc[4][4];
  #pragma unroll
  for (int i=0;i<4;i++)
    #pragma unroll
    for (int j=0;j<4;j++) acc[i][j] = (f32x4){0.f,0.f,0.f,0.f};
  int wm = w>>1, wn = w&1;
  for (int kt=0; kt<16; kt++){
    __syncthreads();
    #pragma unroll
    for (int p=0;p<4;p++){
      int seg = p*4 + w;
      int row = seg*8 + (lane>>3);
      int cch = lane&7;
      gload16(A  + (size_t)(r0+row)*DIN + kt*64 + cch*8, ldsA + seg*512);
      gload16(Bp + (size_t)(n0+row)*DIN + kt*64 + cch*8, ldsB + seg*512);
    }
    __syncthreads();
    #pragma unroll
    for (int ks=0; ks<2; ks++){
      bf16x8 af[4], bf_[4];
      #pragma unroll
      for (int at=0; at<4; at++){
        int row = wm*64 + at*16 + (lane&15);
        int ch = (ks*4 + (lane>>4)) ^ (row&7);
        af[at] = *(const bf16x8*)(ldsA + row*64 + ch*8);
      }
      #pragma unroll
      for (int bt=0; bt<4; bt++){
        int col = wn*64 + bt*16 + (lane&15);
        int ch = (ks*4 + (lane>>4)) ^ (col&7);
        bf_[bt] = *(const bf16x8*)(ldsB + col*64 + ch*8);
      }
      #pragma unroll
      for (int at=0; at<4; at++)
        #pragma unroll
        for (int bt=0; bt<4; bt++)
          acc[at][bt] = __builtin_amdgcn_mfma_f32_16x16x32_bf16(af[at], bf_[bt], acc[at][bt], 0,0,0);
    }
  }
  float bv[4];
  #pragma unroll
  for (int bt=0;bt<4;bt++) bv[bt] = bp[n0 + wn*64 + bt*16 + (lane&15)];
  #pragma unroll
  for (int at=0; at<4; at++)
    #pragma unroll
    for (int bt=0; bt<4; bt++)
      #pragma unroll
      for (int rg=0; rg<4; rg++){
        int row = r0 + wm*64 + at*16 + (lane>>4)*4 + rg;
        int col = n0 + wn*64 + bt*16 + (lane&15);
        op[(size_t)row*G4 + col] = (GXT)(acc[at][bt][rg] + bv[bt]);
      }
}

// ---------------- recurrence: (32*ndirs) WGs = ndirs dirs x 32 col-slices ----------------
// Sync protocol: per-WG counter (one 128B line per dir). Wave 0 = publisher
// (hbuf store -> release fence -> ctr store). Wave 1 = poller (relaxed loads +
// ballot, then ONE acquire fence). Waves run ahead; hOut/hA reuse protected by
// the spin-barrier wave 0 must join before the next overwrite.
template<typename GXT>
__launch_bounds__(256, 1)
__global__ void k_rec(const bf16* __restrict__ Whb, const GXT* __restrict__ gx,
                      bf16* __restrict__ hbuf, u32* __restrict__ ctr,
                      bf16* __restrict__ out0, float* __restrict__ dout,
                      float* __restrict__ hn, float* __restrict__ cn, int layer, int dir0){
  int tid = threadIdx.x, lane = tid&63, w = tid>>6;
  int dl = blockIdx.x >> 5, s = blockIdx.x & 31;
  int d = dir0 + dl;                          // actual direction
  __shared__ __align__(16) bf16 hA[32*512];   // 32KB, XOR-swizzled (via pre-swizzled src)
  __shared__ __align__(16) bf16 hOut[32*16];  // 1KB gather for coalesced writes
  const bf16* Wp = Whb + ((size_t)d*G4 + s*64 + w*16 + (lane&15))*HH;
  bf16x8 bfr[16];
  #pragma unroll
  for (int kk=0; kk<16; kk++) bfr[kk] = *(const bf16x8*)(Wp + kk*32 + (lane>>4)*8);
  float cst[2][4] = {{0,0,0,0},{0,0,0,0}};
  const GXT* gxD = gx + (size_t)dl*MM*G4;
  u32* cbase = ctr + dl*32;
  u32* myctr = cbase + s;
  int q = (lane>>2)&3, hc = lane&3;
  int colg = q*HH + s*16 + w*4 + hc;
  int m0 = lane&15;
  bool hi = (q >= 2), odd = (q & 1);

  for (int t=0; t<TT; t++){
    int tt = d ? (TT-1-t) : t;
    // gx prefetch ISSUED BEFORE THE SPIN (gx immutable -> legal; hides HBM latency)
    float gxv[2][4];
    {
      const GXT* gp = gxD + (size_t)tt*BB*G4 + colg;
      #pragma unroll
      for (int mt=0; mt<2; mt++)
        #pragma unroll
        for (int rg=0; rg<4; rg++)
          gxv[mt][rg] = (float)gp[(size_t)(mt*16 + (lane>>4)*4 + rg)*G4];
    }
    f32x4 acc0 = {0.f,0.f,0.f,0.f}, acc1 = {0.f,0.f,0.f,0.f};
    if (t > 0){
      if (w == 1){   // wave 1 polls: relaxed loads, one line, ballot
        u32 me = lane & 31;
        while (true){
          u32 v = __hip_atomic_load(cbase + me, __ATOMIC_RELAXED, __HIP_MEMORY_SCOPE_AGENT);
          if (__ballot(v >= (u32)t) == ~0ull) break;
          __builtin_amdgcn_s_sleep(2);
        }
        __builtin_amdgcn_fence(__ATOMIC_ACQUIRE, "agent");  // ONE inv per step per WG
      }
      __syncthreads();
      // stage h_{t-1} -> LDS via global_load_lds, pre-swizzled global source
      const bf16* hsrc = hbuf + ((size_t)d*2 + ((t-1)&1))*BB*HH;
      #pragma unroll
      for (int i=0;i<8;i++){
        int chunk = i*256 + tid;
        int b = chunk>>6, j = chunk&63;
        gload16(hsrc + b*HH + ((j ^ (b&7))<<3), hA + (size_t)(i*256 + w*64)*8);
      }
      __syncthreads();
      #pragma unroll
      for (int kk=0; kk<16; kk++){
        int ch = (kk*4 + (lane>>4)) ^ (m0&7);
        bf16x8 a0 = *(const bf16x8*)(hA + m0*HH + ch*8);
        bf16x8 a1 = *(const bf16x8*)(hA + (m0+16)*HH + ch*8);
        acc0 = __builtin_amdgcn_mfma_f32_16x16x32_bf16(a0, bfr[kk], acc0, 0,0,0);
        acc1 = __builtin_amdgcn_mfma_f32_16x16x32_bf16(a1, bfr[kk], acc1, 0,0,0);
      }
    }
    // gates + cell update (gate exchange inside 16-lane groups via shfl_xor)
    #pragma unroll
    for (int mt=0; mt<2; mt++){
      #pragma unroll
      for (int rg=0; rg<4; rg++){
        float gpre = (mt ? acc1[rg] : acc0[rg]) + gxv[mt][rg];
        float x4  = __shfl_xor(gpre, 4);
        float x8  = __shfl_xor(gpre, 8);
        float x12 = __shfl_xor(gpre, 12);
        float a04 = odd ? x4 : gpre,  b04 = odd ? gpre : x4;
        float a812 = odd ? x12 : x8,  b812 = odd ? x8 : x12;
        float ig = hi ? a812 : a04;
        float fg = hi ? b812 : b04;
        float gg = hi ? a04 : a812;
        float og = hi ? b04 : b812;
        float iv = sigmf(ig), fv = sigmf(fg), gv = tanhfast(gg), ov = sigmf(og);
        float c = cst[mt][rg]*fv + iv*gv;
        cst[mt][rg] = c;
        float hvv = ov * tanhfast(c);
        if (q == 0){
          int b = mt*16 + (lane>>4)*4 + rg;
          hOut[b*16 + w*4 + hc] = (bf16)hvv;
          if (layer == 1)   // full-precision output; nontemporal -> fewer dirty L2 lines
            __builtin_nontemporal_store(hvv,
              dout + ((size_t)(b*TT + tt))*(2*HH) + d*HH + s*16 + w*4 + hc);
          if (t == TT-1)
            hn[((size_t)((layer*2+d)*BB + b))*HH + s*16 + w*4 + hc] = hvv;
        }
      }
    }
    if (t == TT-1 && q == 0){
      #pragma unroll
      for (int mt=0; mt<2; mt++)
        #pragma unroll
        for (int rg=0; rg<4; rg++){
          int b = mt*16 + (lane>>4)*4 + rg;
          cn[((size_t)((layer*2+d)*BB + b))*HH + s*16 + w*4 + hc] = cst[mt][rg];
        }
    }
    __syncthreads();      // hOut ready
    // wave 0 publishes while waves 1-3 run ahead to next step's spin
    if (w == 0){
      int b = lane>>1, half = lane&1;
      bf16x8 v = *(const bf16x8*)(hOut + b*16 + half*8);
      *(bf16x8*)(hbuf + ((size_t)d*2 + (t&1))*BB*HH + b*HH + s*16 + half*8) = v;
      if (layer == 0){
        int r = tt*BB + b;
        int chunk = (d*64 + s*2 + half) ^ (r&7);
        __builtin_nontemporal_store(v, (bf16x8*)(out0 + (size_t)r*DIN + chunk*8));
      }
      if (lane == 0){
        __builtin_amdgcn_fence(__ATOMIC_RELEASE, "agent");  // vmcnt drain + wbl2 (wave-level)
        __hip_atomic_store(myctr, (u32)(t+1), __ATOMIC_RELAXED, __HIP_MEMORY_SCOPE_AGENT);
      }
    }
  }
}

extern "C" void kernel_launch(void* const* d_in, const int* in_sizes, int n_in,
                              void* d_out, int out_size, void* d_ws, size_t ws_size,
                              hipStream_t stream){
  const float* x  = (const float*)d_in[0];
  const float* Wx = (const float*)d_in[1];
  const float* bx = (const float*)d_in[2];
  const float* Wh = (const float*)d_in[3];
  const float* bh = (const float*)d_in[4];
  float* outp = (float*)d_out;
  char* ws = (char*)d_ws;

  const size_t szWxt  = (size_t)4*G4*DIN*2;   // 16.8 MB
  const size_t szWhb  = (size_t)4*G4*HH*2;    // 8.4 MB
  const size_t szBsum = (size_t)4*G4*4;
  const size_t szXO   = (size_t)MM*DIN*2;     // 33.6 MB
  const size_t szHbuf = (size_t)2*2*BB*HH*2;
  const size_t szCtr  = 512;                  // [layer][dir][32] u32

  // mode 0: f32 gx, both dirs, xo/out0 shared        (~327 MB)
  // mode 1: bf16 gx, both dirs, xo/out0 shared       (~193 MB)
  // mode 2: bf16 gx, one dir, separate out0, serial  (~160 MB)
  int mode = -1;
  size_t oWxt=0,oWhb=0,oBsum=0,oXO=0,oOut0=0,oHbuf=0,oCtr=0,oGx=0;
  for (int m=0; m<3 && mode<0; m++){
    size_t off = 0;
    auto take = [&](size_t b)->size_t{ size_t r = off; off = (off + b + 255) & ~(size_t)255; return r; };
    oWxt = take(szWxt); oWhb = take(szWhb); oBsum = take(szBsum);
    oXO  = take(szXO);
    oOut0 = (m==2) ? take(szXO) : oXO;
    oHbuf = take(szHbuf); oCtr = take(szCtr);
    size_t gxb = (m==0) ? (size_t)2*MM*G4*4 : (m==1) ? (size_t)2*MM*G4*2 : (size_t)MM*G4*2;
    oGx = take(gxb);
    if (off <= ws_size) mode = m;
  }
  if (mode < 0){
    k_dbg<<<1, 1, 0, stream>>>(outp, (float)((double)ws_size / 1048576.0));
    return;
  }

  bf16* Wxt  = (bf16*)(ws + oWxt);
  bf16* Whb  = (bf16*)(ws + oWhb);
  float* bsum= (float*)(ws + oBsum);
  bf16* xo   = (bf16*)(ws + oXO);
  bf16* out0 = (bf16*)(ws + oOut0);
  bf16* hbuf = (bf16*)(ws + oHbuf);
  u32*  ctr  = (u32*)(ws + oCtr);
  void* gxp  = (void*)(ws + oGx);

  float* hn = outp + (size_t)BB*TT*2*HH;
  float* cn = hn + (size_t)4*BB*HH;

  k_prep_bias<<<32, 256, 0, stream>>>(bx, bh, bsum, ctr);
  k_xswz<<<(MM*128)/256, 256, 0, stream>>>(x, xo);
  k_twx<<<dim3(16,32,4), 256, 0, stream>>>(Wx, Wxt);
  k_twh<<<dim3(8,32,4), 256, 0, stream>>>(Wh, Whb);

  if (mode == 0){
    float* gx = (float*)gxp;
    for (int layer=0; layer<2; layer++){
      k_gemm<float><<<dim3(16,128,2), 256, 0, stream>>>(xo, Wxt + (size_t)layer*2*G4*DIN,
                                                        bsum + layer*2*G4, gx);
      k_rec<float><<<64, 256, 0, stream>>>(Whb + (size_t)layer*2*G4*HH, gx, hbuf,
                                           ctr + layer*64, out0, outp, hn, cn, layer, 0);
    }
  } else if (mode == 1){
    bf16* gx = (bf16*)gxp;
    for (int layer=0; layer<2; layer++){
      k_gemm<bf16><<<dim3(16,128,2), 256, 0, stream>>>(xo, Wxt + (size_t)layer*2*G4*DIN,
                                                       bsum + layer*2*G4, gx);
      k_rec<bf16><<<64, 256, 0, stream>>>(Whb + (size_t)layer*2*G4*HH, gx, hbuf,
                                          ctr + layer*64, out0, outp, hn, cn, layer, 0);
    }
  } else {
    bf16* gx = (bf16*)gxp;
    for (int layer=0; layer<2; layer++){
      const bf16* A = layer ? out0 : xo;
      for (int dd=0; dd<2; dd++){
        k_gemm<bf16><<<dim3(16,128,1), 256, 0, stream>>>(A, Wxt + (size_t)(layer*2+dd)*G4*DIN,
                                                         bsum + (layer*2+dd)*G4, gx);
        k_rec<bf16><<<32, 256, 0, stream>>>(Whb + (size_t)layer*2*G4*HH, gx, hbuf,
                                            ctr + (layer*2+dd)*32, out0, outp, hn, cn, layer, dd);
      }
    }
  }
}

// Round 5
// 6716.011 us; speedup vs baseline: 2.5353x; 1.2765x over previous
//
#include <hip/hip_runtime.h>
#include <hip/hip_bf16.h>

#define DEV __device__ __forceinline__

typedef __bf16 bf16;
typedef __bf16 bf16x8 __attribute__((ext_vector_type(8)));
typedef float f32x4 __attribute__((ext_vector_type(4)));
typedef int i32x4 __attribute__((ext_vector_type(4)));
typedef unsigned int u32;

// problem constants
#define BB 32
#define TT 512
#define DIN 1024
#define HH 512
#define G4 2048          // 4H
#define MM (TT*BB)       // 16384 rows (t-major: r = t*32 + b)

DEV float sigmf(float x){ return 1.0f/(1.0f + __expf(-x)); }
DEV float tanhfast(float x){ return 1.0f - 2.0f/(__expf(2.0f*x)+1.0f); }

DEV void gload16(const void* g, void* l){
  __builtin_amdgcn_global_load_lds((const __attribute__((address_space(1))) void*)g,
                                   (__attribute__((address_space(3))) void*)l, 16, 0, 0);
}

// coherence-point (bypass L1+L2) accessors — cross-XCD visible without cache flushes
// NOTE: ext_vector types (not HIP's struct int4) so 'v' binds a VGPR quad.
DEV i32x4 cload16(const void* p){
  i32x4 v;
  asm volatile("global_load_dwordx4 %0, %1, off sc0 sc1"
               : "=&v"(v) : "v"(p) : "memory");
  return v;
}
DEV void cstore16(void* p, i32x4 v){
  asm volatile("global_store_dwordx4 %0, %1, off sc0 sc1"
               :: "v"(p), "v"(v) : "memory");
}
DEV void cstore4(void* p, u32 v){
  asm volatile("global_store_dword %0, %1, off sc0 sc1"
               :: "v"(p), "v"(v) : "memory");
}
DEV u32 cload4(const void* p){
  u32 v;
  asm volatile("global_load_dword %0, %1, off sc0 sc1\n\ts_waitcnt vmcnt(0)"
               : "=&v"(v) : "v"(p) : "memory");
  return v;
}
DEV void waitvm0(){ asm volatile("s_waitcnt vmcnt(0)" ::: "memory"); }

// ---------------- debug: report ws_size via absmax ----------------
__global__ void k_dbg(float* out, float v){ out[0] = v; }

// ---------------- prep: bias sum + counter zero ----------------
__global__ void k_prep_bias(const float* __restrict__ bx, const float* __restrict__ bh,
                            float* __restrict__ bsum, u32* __restrict__ ctr){
  int gid = blockIdx.x*256 + threadIdx.x;
  if (gid < 4*G4) bsum[gid] = bx[gid] + bh[gid];
  if (gid < 128) cstore4(ctr + gid, 0u);   // [layer][dir][32], at coherence point
}

// ---------------- x -> bf16, row r = t*32+b, XOR-swizzled 16B chunks ----------------
__global__ void k_xswz(const float* __restrict__ x, bf16* __restrict__ xs){
  int gid = blockIdx.x*256 + threadIdx.x;   // 16384*128
  int r = gid >> 7, kc = gid & 127;
  int b = r & 31, t = r >> 5;
  const float* px = x + ((size_t)b*TT + t)*DIN + kc*8;
  float4 v0 = *(const float4*)px;
  float4 v1 = *(const float4*)(px+4);
  bf16x8 o;
  o[0]=(bf16)v0.x; o[1]=(bf16)v0.y; o[2]=(bf16)v0.z; o[3]=(bf16)v0.w;
  o[4]=(bf16)v1.x; o[5]=(bf16)v1.y; o[6]=(bf16)v1.z; o[7]=(bf16)v1.w;
  *(bf16x8*)(xs + (size_t)r*DIN + ((kc ^ (r&7))<<3)) = o;
}

// ---------------- Wx: [ld][k=1024][n=2048] f32 -> [ld][n][k] bf16, swizzled ----------------
__global__ void k_twx(const float* __restrict__ Wx, bf16* __restrict__ Wxt){
  int ld = blockIdx.z;
  int k0 = blockIdx.x*64, n0 = blockIdx.y*64;
  const float* in = Wx + (size_t)ld*DIN*G4;
  bf16* outp = Wxt + (size_t)ld*G4*DIN;
  __shared__ float tile[64][68];
  int tid = threadIdx.x;
  #pragma unroll
  for (int rr=0; rr<4; rr++){
    int row = rr*16 + (tid>>4); int c4 = (tid&15)*4;
    float4 v = *(const float4*)(in + (size_t)(k0+row)*G4 + n0 + c4);
    *(float4*)&tile[row][c4] = v;
  }
  __syncthreads();
  #pragma unroll
  for (int uu=0; uu<2; uu++){
    int u = uu*256 + tid;
    int nn = u>>3, ck = u&7;
    bf16x8 o;
    #pragma unroll
    for (int j=0;j<8;j++) o[j] = (bf16)tile[ck*8+j][nn];
    int ncol = n0 + nn;
    int kcg = (k0>>3) + ck;
    *(bf16x8*)(outp + (size_t)ncol*DIN + ((size_t)(kcg ^ (ncol&7))<<3)) = o;
  }
}

// ---------------- Wh: [ld][k=512][n=2048] f32 -> [ld][cc][k] bf16 (col remap) ----------------
__global__ void k_twh(const float* __restrict__ Wh, bf16* __restrict__ Whb){
  int ld = blockIdx.z;
  int k0 = blockIdx.x*64, n0 = blockIdx.y*64;
  const float* in = Wh + (size_t)ld*HH*G4;
  bf16* outp = Whb + (size_t)ld*G4*HH;
  __shared__ float tile[64][68];
  int tid = threadIdx.x;
  #pragma unroll
  for (int rr=0; rr<4; rr++){
    int row = rr*16 + (tid>>4); int c4 = (tid&15)*4;
    float4 v = *(const float4*)(in + (size_t)(k0+row)*G4 + n0 + c4);
    *(float4*)&tile[row][c4] = v;
  }
  __syncthreads();
  #pragma unroll
  for (int uu=0; uu<2; uu++){
    int u = uu*256 + tid;
    int nn = u>>3, ck = u&7;
    bf16x8 o;
    #pragma unroll
    for (int j=0;j<8;j++) o[j] = (bf16)tile[ck*8+j][nn];
    int n = n0 + nn;
    int q = n >> 9, rem = n & 511;
    int s = rem >> 4, wq = (rem >> 2) & 3, hcv = rem & 3;
    int cc = s*64 + wq*16 + q*4 + hcv;   // gate-interleaved col order
    *(bf16x8*)(outp + (size_t)cc*HH + k0 + ck*8) = o;
  }
}

// ---------------- gx GEMM: [16384,1024]bf16 @ [1024,2048]bf16 -> GXT (+bias) ----------------
template<typename GXT>
__launch_bounds__(256, 1)
__global__ void k_gemm(const bf16* __restrict__ A, const bf16* __restrict__ Bw,
                       const float* __restrict__ bias, GXT* __restrict__ out){
  int d = blockIdx.z;
  const bf16* Bp = Bw + (size_t)d*G4*DIN;
  const float* bp = bias + d*G4;
  GXT* op = out + (size_t)d*MM*G4;
  int n0 = blockIdx.x*128, r0 = blockIdx.y*128;
  int tid = threadIdx.x, lane = tid&63, w = tid>>6;
  __shared__ __align__(16) bf16 ldsA[128*64];
  __shared__ __align__(16) bf16 ldsB[128*64];
  f32x4 acc[4][4];
  #pragma unroll
  for (int i=0;i<4;i++)
    #pragma unroll
    for (int j=0;j<4;j++) acc[i][j] = (f32x4){0.f,0.f,0.f,0.f};
  int wm = w>>1, wn = w&1;
  for (int kt=0; kt<16; kt++){
    __syncthreads();
    #pragma unroll
    for (int p=0;p<4;p++){
      int seg = p*4 + w;
      int row = seg*8 + (lane>>3);
      int cch = lane&7;
      gload16(A  + (size_t)(r0+row)*DIN + kt*64 + cch*8, ldsA + seg*512);
      gload16(Bp + (size_t)(n0+row)*DIN + kt*64 + cch*8, ldsB + seg*512);
    }
    __syncthreads();
    #pragma unroll
    for (int ks=0; ks<2; ks++){
      bf16x8 af[4], bf_[4];
      #pragma unroll
      for (int at=0; at<4; at++){
        int row = wm*64 + at*16 + (lane&15);
        int ch = (ks*4 + (lane>>4)) ^ (row&7);
        af[at] = *(const bf16x8*)(ldsA + row*64 + ch*8);
      }
      #pragma unroll
      for (int bt=0; bt<4; bt++){
        int col = wn*64 + bt*16 + (lane&15);
        int ch = (ks*4 + (lane>>4)) ^ (col&7);
        bf_[bt] = *(const bf16x8*)(ldsB + col*64 + ch*8);
      }
      #pragma unroll
      for (int at=0; at<4; at++)
        #pragma unroll
        for (int bt=0; bt<4; bt++)
          acc[at][bt] = __builtin_amdgcn_mfma_f32_16x16x32_bf16(af[at], bf_[bt], acc[at][bt], 0,0,0);
    }
  }
  float bv[4];
  #pragma unroll
  for (int bt=0;bt<4;bt++) bv[bt] = bp[n0 + wn*64 + bt*16 + (lane&15)];
  #pragma unroll
  for (int at=0; at<4; at++)
    #pragma unroll
    for (int bt=0; bt<4; bt++)
      #pragma unroll
      for (int rg=0; rg<4; rg++){
        int row = r0 + wm*64 + at*16 + (lane>>4)*4 + rg;
        int col = n0 + wn*64 + bt*16 + (lane&15);
        op[(size_t)row*G4 + col] = (GXT)(acc[at][bt][rg] + bv[bt]);
      }
}

// ---------------- recurrence: (32*ndirs) WGs = ndirs dirs x 32 col-slices ----------------
// Cache-op-free sync: all h/ctr traffic via sc0 sc1 (coherence-point) asm ops.
// Wave 0 publishes (16B stores -> vmcnt(0) -> ctr store); wave 1 polls (sc0 sc1
// loads + ballot). NO fences -> L2 (gx stream, weights) never flushed/invalidated.
template<typename GXT>
__launch_bounds__(256, 1)
__global__ void k_rec(const bf16* __restrict__ Whb, const GXT* __restrict__ gx,
                      bf16* __restrict__ hbuf, u32* __restrict__ ctr,
                      bf16* __restrict__ out0, float* __restrict__ dout,
                      float* __restrict__ hn, float* __restrict__ cn, int layer, int dir0){
  int tid = threadIdx.x, lane = tid&63, w = tid>>6;
  int dl = blockIdx.x >> 5, s = blockIdx.x & 31;
  int d = dir0 + dl;                          // actual direction
  __shared__ __align__(16) bf16 hA[32*512];   // 32KB, XOR-swizzled (write-side swizzle)
  __shared__ __align__(16) bf16 hOut[32*16];  // 1KB gather for coalesced publishes
  const bf16* Wp = Whb + ((size_t)d*G4 + s*64 + w*16 + (lane&15))*HH;
  bf16x8 bfr[16];
  #pragma unroll
  for (int kk=0; kk<16; kk++) bfr[kk] = *(const bf16x8*)(Wp + kk*32 + (lane>>4)*8);
  float cst[2][4] = {{0,0,0,0},{0,0,0,0}};
  const GXT* gxD = gx + (size_t)dl*MM*G4;
  u32* cbase = ctr + dl*32;
  u32* myctr = cbase + s;
  int q = (lane>>2)&3, hc = lane&3;
  int colg = q*HH + s*16 + w*4 + hc;
  int m0 = lane&15;
  bool hi = (q >= 2), odd = (q & 1);

  for (int t=0; t<TT; t++){
    int tt = d ? (TT-1-t) : t;
    // gx prefetch ISSUED BEFORE THE SPIN (gx immutable -> legal; hides HBM latency)
    float gxv[2][4];
    {
      const GXT* gp = gxD + (size_t)tt*BB*G4 + colg;
      #pragma unroll
      for (int mt=0; mt<2; mt++)
        #pragma unroll
        for (int rg=0; rg<4; rg++)
          gxv[mt][rg] = (float)gp[(size_t)(mt*16 + (lane>>4)*4 + rg)*G4];
    }
    f32x4 acc0 = {0.f,0.f,0.f,0.f}, acc1 = {0.f,0.f,0.f,0.f};
    if (t > 0){
      if (w == 1){   // wave 1 polls the whole counter line; no fences needed
        u32 me = lane & 31;
        while (true){
          u32 v = cload4(cbase + me);
          if (__ballot(v >= (u32)t) == ~0ull) break;
          __builtin_amdgcn_s_sleep(2);
        }
      }
      __syncthreads();
      // stage h_{t-1} -> LDS: coherence-point loads to regs, swizzled ds_write
      const bf16* hsrc = hbuf + ((size_t)d*2 + ((t-1)&1))*BB*HH;
      i32x4 hreg[8];
      #pragma unroll
      for (int i=0;i<8;i++){
        int chunk = i*256 + tid;
        int b = chunk>>6, j = chunk&63;
        hreg[i] = cload16(hsrc + b*HH + j*8);
      }
      waitvm0();
      __builtin_amdgcn_sched_barrier(0);
      #pragma unroll
      for (int i=0;i<8;i++){
        int chunk = i*256 + tid;
        int b = chunk>>6, j = chunk&63;
        *(i32x4*)(hA + b*HH + ((j ^ (b&7))<<3)) = hreg[i];
      }
      __syncthreads();
      #pragma unroll
      for (int kk=0; kk<16; kk++){
        int ch = (kk*4 + (lane>>4)) ^ (m0&7);
        bf16x8 a0 = *(const bf16x8*)(hA + m0*HH + ch*8);
        bf16x8 a1 = *(const bf16x8*)(hA + (m0+16)*HH + ch*8);
        acc0 = __builtin_amdgcn_mfma_f32_16x16x32_bf16(a0, bfr[kk], acc0, 0,0,0);
        acc1 = __builtin_amdgcn_mfma_f32_16x16x32_bf16(a1, bfr[kk], acc1, 0,0,0);
      }
    }
    // gates + cell update (gate exchange inside 16-lane groups via shfl_xor)
    #pragma unroll
    for (int mt=0; mt<2; mt++){
      #pragma unroll
      for (int rg=0; rg<4; rg++){
        float gpre = (mt ? acc1[rg] : acc0[rg]) + gxv[mt][rg];
        float x4  = __shfl_xor(gpre, 4);
        float x8  = __shfl_xor(gpre, 8);
        float x12 = __shfl_xor(gpre, 12);
        float a04 = odd ? x4 : gpre,  b04 = odd ? gpre : x4;
        float a812 = odd ? x12 : x8,  b812 = odd ? x8 : x12;
        float ig = hi ? a812 : a04;
        float fg = hi ? b812 : b04;
        float gg = hi ? a04 : a812;
        float og = hi ? b04 : b812;
        float iv = sigmf(ig), fv = sigmf(fg), gv = tanhfast(gg), ov = sigmf(og);
        float c = cst[mt][rg]*fv + iv*gv;
        cst[mt][rg] = c;
        float hvv = ov * tanhfast(c);
        if (q == 0){
          int b = mt*16 + (lane>>4)*4 + rg;
          hOut[b*16 + w*4 + hc] = (bf16)hvv;
          if (layer == 1)   // full-precision output; nt keeps L2 clean for gx
            __builtin_nontemporal_store(hvv,
              dout + ((size_t)(b*TT + tt))*(2*HH) + d*HH + s*16 + w*4 + hc);
          if (t == TT-1)
            hn[((size_t)((layer*2+d)*BB + b))*HH + s*16 + w*4 + hc] = hvv;
        }
      }
    }
    if (t == TT-1 && q == 0){
      #pragma unroll
      for (int mt=0; mt<2; mt++)
        #pragma unroll
        for (int rg=0; rg<4; rg++){
          int b = mt*16 + (lane>>4)*4 + rg;
          cn[((size_t)((layer*2+d)*BB + b))*HH + s*16 + w*4 + hc] = cst[mt][rg];
        }
    }
    __syncthreads();      // hOut ready
    // wave 0 publishes while waves 1-3 run ahead to next step's spin
    if (w == 0){
      int b = lane>>1, half = lane&1;
      i32x4 v = *(const i32x4*)(hOut + b*16 + half*8);
      cstore16(hbuf + ((size_t)d*2 + (t&1))*BB*HH + b*HH + s*16 + half*8, v);
      waitvm0();          // h at coherence point before counter bump
      if (lane == 0) cstore4(myctr, (u32)(t+1));
      if (layer == 0){    // out0 handoff: normal nt stores, kernel-end flush covers it
        int r = tt*BB + b;
        int chunk = (d*64 + s*2 + half) ^ (r&7);
        __builtin_nontemporal_store(*(const bf16x8*)&v,
                                    (bf16x8*)(out0 + (size_t)r*DIN + chunk*8));
      }
    }
  }
}

extern "C" void kernel_launch(void* const* d_in, const int* in_sizes, int n_in,
                              void* d_out, int out_size, void* d_ws, size_t ws_size,
                              hipStream_t stream){
  const float* x  = (const float*)d_in[0];
  const float* Wx = (const float*)d_in[1];
  const float* bx = (const float*)d_in[2];
  const float* Wh = (const float*)d_in[3];
  const float* bh = (const float*)d_in[4];
  float* outp = (float*)d_out;
  char* ws = (char*)d_ws;

  const size_t szWxt  = (size_t)4*G4*DIN*2;   // 16.8 MB
  const size_t szWhb  = (size_t)4*G4*HH*2;    // 8.4 MB
  const size_t szBsum = (size_t)4*G4*4;
  const size_t szXO   = (size_t)MM*DIN*2;     // 33.6 MB
  const size_t szHbuf = (size_t)2*2*BB*HH*2;
  const size_t szCtr  = 512;                  // [layer][dir][32] u32

  // mode 0: f32 gx, both dirs, xo/out0 shared        (~327 MB)
  // mode 1: bf16 gx, both dirs, xo/out0 shared       (~193 MB)
  // mode 2: bf16 gx, one dir, separate out0, serial  (~160 MB)
  int mode = -1;
  size_t oWxt=0,oWhb=0,oBsum=0,oXO=0,oOut0=0,oHbuf=0,oCtr=0,oGx=0;
  for (int m=0; m<3 && mode<0; m++){
    size_t off = 0;
    auto take = [&](size_t b)->size_t{ size_t r = off; off = (off + b + 255) & ~(size_t)255; return r; };
    oWxt = take(szWxt); oWhb = take(szWhb); oBsum = take(szBsum);
    oXO  = take(szXO);
    oOut0 = (m==2) ? take(szXO) : oXO;
    oHbuf = take(szHbuf); oCtr = take(szCtr);
    size_t gxb = (m==0) ? (size_t)2*MM*G4*4 : (m==1) ? (size_t)2*MM*G4*2 : (size_t)MM*G4*2;
    oGx = take(gxb);
    if (off <= ws_size) mode = m;
  }
  if (mode < 0){
    k_dbg<<<1, 1, 0, stream>>>(outp, (float)((double)ws_size / 1048576.0));
    return;
  }

  bf16* Wxt  = (bf16*)(ws + oWxt);
  bf16* Whb  = (bf16*)(ws + oWhb);
  float* bsum= (float*)(ws + oBsum);
  bf16* xo   = (bf16*)(ws + oXO);
  bf16* out0 = (bf16*)(ws + oOut0);
  bf16* hbuf = (bf16*)(ws + oHbuf);
  u32*  ctr  = (u32*)(ws + oCtr);
  void* gxp  = (void*)(ws + oGx);

  float* hn = outp + (size_t)BB*TT*2*HH;
  float* cn = hn + (size_t)4*BB*HH;

  k_prep_bias<<<32, 256, 0, stream>>>(bx, bh, bsum, ctr);
  k_xswz<<<(MM*128)/256, 256, 0, stream>>>(x, xo);
  k_twx<<<dim3(16,32,4), 256, 0, stream>>>(Wx, Wxt);
  k_twh<<<dim3(8,32,4), 256, 0, stream>>>(Wh, Whb);

  if (mode == 0){
    float* gx = (float*)gxp;
    for (int layer=0; layer<2; layer++){
      k_gemm<float><<<dim3(16,128,2), 256, 0, stream>>>(xo, Wxt + (size_t)layer*2*G4*DIN,
                                                        bsum + layer*2*G4, gx);
      k_rec<float><<<64, 256, 0, stream>>>(Whb + (size_t)layer*2*G4*HH, gx, hbuf,
                                           ctr + layer*64, out0, outp, hn, cn, layer, 0);
    }
  } else if (mode == 1){
    bf16* gx = (bf16*)gxp;
    for (int layer=0; layer<2; layer++){
      k_gemm<bf16><<<dim3(16,128,2), 256, 0, stream>>>(xo, Wxt + (size_t)layer*2*G4*DIN,
                                                       bsum + layer*2*G4, gx);
      k_rec<bf16><<<64, 256, 0, stream>>>(Whb + (size_t)layer*2*G4*HH, gx, hbuf,
                                          ctr + layer*64, out0, outp, hn, cn, layer, 0);
    }
  } else {
    bf16* gx = (bf16*)gxp;
    for (int layer=0; layer<2; layer++){
      const bf16* A = layer ? out0 : xo;
      for (int dd=0; dd<2; dd++){
        k_gemm<bf16><<<dim3(16,128,1), 256, 0, stream>>>(A, Wxt + (size_t)(layer*2+dd)*G4*DIN,
                                                         bsum + (layer*2+dd)*G4, gx);
        k_rec<bf16><<<32, 256, 0, stream>>>(Whb + (size_t)layer*2*G4*HH, gx, hbuf,
                                            ctr + (layer*2+dd)*32, out0, outp, hn, cn, layer, dd);
      }
    }
  }
}

// Round 6
// 5624.295 us; speedup vs baseline: 3.0274x; 1.1941x over previous
//
#include <hip/hip_runtime.h>
#include <hip/hip_bf16.h>

#define DEV __device__ __forceinline__

typedef __bf16 bf16;
typedef __bf16 bf16x8 __attribute__((ext_vector_type(8)));
typedef float f32x4 __attribute__((ext_vector_type(4)));
typedef int i32x4 __attribute__((ext_vector_type(4)));
typedef unsigned int u32;
typedef unsigned long long u64;

// problem constants
#define BB 32
#define TT 512
#define DIN 1024
#define HH 512
#define G4 2048          // 4H
#define MM (TT*BB)       // 16384 rows (t-major: r = t*32 + b)
#define TAGMAGIC 0x5A000000u

DEV float sigmf(float x){ return 1.0f/(1.0f + __expf(-x)); }
DEV float tanhfast(float x){ return 1.0f - 2.0f/(__expf(2.0f*x)+1.0f); }

DEV void gload16(const void* g, void* l){
  __builtin_amdgcn_global_load_lds((const __attribute__((address_space(1))) void*)g,
                                   (__attribute__((address_space(3))) void*)l, 16, 0, 0);
}

// coherence-point (bypass L1+L2) accessors — cross-XCD visible without cache flushes
DEV i32x4 cload16(const void* p){
  i32x4 v;
  asm volatile("global_load_dwordx4 %0, %1, off sc0 sc1"
               : "=&v"(v) : "v"(p) : "memory");
  return v;
}
DEV void cstore16(void* p, i32x4 v){
  asm volatile("global_store_dwordx4 %0, %1, off sc0 sc1"
               :: "v"(p), "v"(v) : "memory");
}
DEV void waitvm0(){ asm volatile("s_waitcnt vmcnt(0)" ::: "memory"); }

// ---------------- debug: report ws_size via absmax ----------------
__global__ void k_dbg(float* out, float v){ out[0] = v; }

// ---------------- prep: bias sum ----------------
__global__ void k_prep_bias(const float* __restrict__ bx, const float* __restrict__ bh,
                            float* __restrict__ bsum){
  int gid = blockIdx.x*256 + threadIdx.x;
  if (gid < 4*G4) bsum[gid] = bx[gid] + bh[gid];
}

// ---------------- x -> bf16, row r = t*32+b, XOR-swizzled 16B chunks ----------------
__global__ void k_xswz(const float* __restrict__ x, bf16* __restrict__ xs){
  int gid = blockIdx.x*256 + threadIdx.x;   // 16384*128
  int r = gid >> 7, kc = gid & 127;
  int b = r & 31, t = r >> 5;
  const float* px = x + ((size_t)b*TT + t)*DIN + kc*8;
  float4 v0 = *(const float4*)px;
  float4 v1 = *(const float4*)(px+4);
  bf16x8 o;
  o[0]=(bf16)v0.x; o[1]=(bf16)v0.y; o[2]=(bf16)v0.z; o[3]=(bf16)v0.w;
  o[4]=(bf16)v1.x; o[5]=(bf16)v1.y; o[6]=(bf16)v1.z; o[7]=(bf16)v1.w;
  *(bf16x8*)(xs + (size_t)r*DIN + ((kc ^ (r&7))<<3)) = o;
}

// ---------------- Wx: [ld][k=1024][n=2048] f32 -> [ld][n][k] bf16, swizzled ----------------
__global__ void k_twx(const float* __restrict__ Wx, bf16* __restrict__ Wxt){
  int ld = blockIdx.z;
  int k0 = blockIdx.x*64, n0 = blockIdx.y*64;
  const float* in = Wx + (size_t)ld*DIN*G4;
  bf16* outp = Wxt + (size_t)ld*G4*DIN;
  __shared__ float tile[64][68];
  int tid = threadIdx.x;
  #pragma unroll
  for (int rr=0; rr<4; rr++){
    int row = rr*16 + (tid>>4); int c4 = (tid&15)*4;
    float4 v = *(const float4*)(in + (size_t)(k0+row)*G4 + n0 + c4);
    *(float4*)&tile[row][c4] = v;
  }
  __syncthreads();
  #pragma unroll
  for (int uu=0; uu<2; uu++){
    int u = uu*256 + tid;
    int nn = u>>3, ck = u&7;
    bf16x8 o;
    #pragma unroll
    for (int j=0;j<8;j++) o[j] = (bf16)tile[ck*8+j][nn];
    int ncol = n0 + nn;
    int kcg = (k0>>3) + ck;
    *(bf16x8*)(outp + (size_t)ncol*DIN + ((size_t)(kcg ^ (ncol&7))<<3)) = o;
  }
}

// ---------------- Wh: [ld][k=512][n=2048] f32 -> [ld][cc][k] bf16 (col remap) ----------------
__global__ void k_twh(const float* __restrict__ Wh, bf16* __restrict__ Whb){
  int ld = blockIdx.z;
  int k0 = blockIdx.x*64, n0 = blockIdx.y*64;
  const float* in = Wh + (size_t)ld*HH*G4;
  bf16* outp = Whb + (size_t)ld*G4*HH;
  __shared__ float tile[64][68];
  int tid = threadIdx.x;
  #pragma unroll
  for (int rr=0; rr<4; rr++){
    int row = rr*16 + (tid>>4); int c4 = (tid&15)*4;
    float4 v = *(const float4*)(in + (size_t)(k0+row)*G4 + n0 + c4);
    *(float4*)&tile[row][c4] = v;
  }
  __syncthreads();
  #pragma unroll
  for (int uu=0; uu<2; uu++){
    int u = uu*256 + tid;
    int nn = u>>3, ck = u&7;
    bf16x8 o;
    #pragma unroll
    for (int j=0;j<8;j++) o[j] = (bf16)tile[ck*8+j][nn];
    int n = n0 + nn;
    int q = n >> 9, rem = n & 511;
    int s = rem >> 4, wq = (rem >> 2) & 3, hcv = rem & 3;
    int cc = s*64 + wq*16 + q*4 + hcv;   // gate-interleaved col order
    *(bf16x8*)(outp + (size_t)cc*HH + k0 + ck*8) = o;
  }
}

// ---------------- gx GEMM: [16384,1024]bf16 @ [1024,2048]bf16 -> GXT (+bias) ----------------
template<typename GXT>
__launch_bounds__(256, 1)
__global__ void k_gemm(const bf16* __restrict__ A, const bf16* __restrict__ Bw,
                       const float* __restrict__ bias, GXT* __restrict__ out){
  int d = blockIdx.z;
  const bf16* Bp = Bw + (size_t)d*G4*DIN;
  const float* bp = bias + d*G4;
  GXT* op = out + (size_t)d*MM*G4;
  int n0 = blockIdx.x*128, r0 = blockIdx.y*128;
  int tid = threadIdx.x, lane = tid&63, w = tid>>6;
  __shared__ __align__(16) bf16 ldsA[128*64];
  __shared__ __align__(16) bf16 ldsB[128*64];
  f32x4 acc[4][4];
  #pragma unroll
  for (int i=0;i<4;i++)
    #pragma unroll
    for (int j=0;j<4;j++) acc[i][j] = (f32x4){0.f,0.f,0.f,0.f};
  int wm = w>>1, wn = w&1;
  for (int kt=0; kt<16; kt++){
    __syncthreads();
    #pragma unroll
    for (int p=0;p<4;p++){
      int seg = p*4 + w;
      int row = seg*8 + (lane>>3);
      int cch = lane&7;
      gload16(A  + (size_t)(r0+row)*DIN + kt*64 + cch*8, ldsA + seg*512);
      gload16(Bp + (size_t)(n0+row)*DIN + kt*64 + cch*8, ldsB + seg*512);
    }
    __syncthreads();
    #pragma unroll
    for (int ks=0; ks<2; ks++){
      bf16x8 af[4], bf_[4];
      #pragma unroll
      for (int at=0; at<4; at++){
        int row = wm*64 + at*16 + (lane&15);
        int ch = (ks*4 + (lane>>4)) ^ (row&7);
        af[at] = *(const bf16x8*)(ldsA + row*64 + ch*8);
      }
      #pragma unroll
      for (int bt=0; bt<4; bt++){
        int col = wn*64 + bt*16 + (lane&15);
        int ch = (ks*4 + (lane>>4)) ^ (col&7);
        bf_[bt] = *(const bf16x8*)(ldsB + col*64 + ch*8);
      }
      #pragma unroll
      for (int at=0; at<4; at++)
        #pragma unroll
        for (int bt=0; bt<4; bt++)
          acc[at][bt] = __builtin_amdgcn_mfma_f32_16x16x32_bf16(af[at], bf_[bt], acc[at][bt], 0,0,0);
    }
  }
  float bv[4];
  #pragma unroll
  for (int bt=0;bt<4;bt++) bv[bt] = bp[n0 + wn*64 + bt*16 + (lane&15)];
  #pragma unroll
  for (int at=0; at<4; at++)
    #pragma unroll
    for (int bt=0; bt<4; bt++)
      #pragma unroll
      for (int rg=0; rg<4; rg++){
        int row = r0 + wm*64 + at*16 + (lane>>4)*4 + rg;
        int col = n0 + wn*64 + bt*16 + (lane&15);
        op[(size_t)row*G4 + col] = (GXT)(acc[at][bt][rg] + bv[bt]);
      }
}

// ---------------- recurrence: (32*ndirs) WGs = ndirs dirs x 32 col-slices ----------------
// Tagged-unit protocol: 16B = {4xbf16 | u32 tag | pad}. Publish is fire-and-forget
// sc0sc1 stores; consumer's poll IS the data load (tag check in-register, retry
// stale units only). No fences, no flags, no publish-ack round trip.
// WAW (slot t vs t+2) ordered by the staging vmcnt(0) every wave runs at t+1.
template<typename GXT>
__launch_bounds__(256, 1)
__global__ void k_rec(const bf16* __restrict__ Whb, const GXT* __restrict__ gx,
                      char* __restrict__ hbT,
                      bf16* __restrict__ out0, float* __restrict__ dout,
                      float* __restrict__ hn, float* __restrict__ cn, int layer, int dir0){
  int tid = threadIdx.x, lane = tid&63, w = tid>>6;
  int dl = blockIdx.x >> 5, s = blockIdx.x & 31;
  int d = dir0 + dl;                          // actual direction
  __shared__ __align__(16) bf16 hA[32*512];   // 32KB, XOR-swizzled
  __shared__ __align__(8) unsigned short hP[4*128]; // per-wave publish pack (256B each)
  const bf16* Wp = Whb + ((size_t)d*G4 + s*64 + w*16 + (lane&15))*HH;
  bf16x8 bfr[16];
  #pragma unroll
  for (int kk=0; kk<16; kk++) bfr[kk] = *(const bf16x8*)(Wp + kk*32 + (lane>>4)*8);
  float cst[2][4] = {{0,0,0,0},{0,0,0,0}};
  const GXT* gxD = gx + (size_t)dl*MM*G4;
  const u32 tagbase = TAGMAGIC + (u32)((layer*2 + d)*TT);  // tag(h_tau) = tagbase + tau + 1
  int q = (lane>>2)&3, hc = lane&3;
  int colg = q*HH + s*16 + w*4 + hc;
  int m0 = lane&15;
  bool hi = (q >= 2), odd = (q & 1);

  for (int t=0; t<TT; t++){
    int tt = d ? (TT-1-t) : t;
    // gx prefetch: raw loads early, convert late (hidden under staging wait)
    GXT gxr[2][4];
    {
      const GXT* gp = gxD + (size_t)tt*BB*G4 + colg;
      #pragma unroll
      for (int mt=0; mt<2; mt++)
        #pragma unroll
        for (int rg=0; rg<4; rg++)
          gxr[mt][rg] = gp[(size_t)(mt*16 + (lane>>4)*4 + rg)*G4];
    }
    f32x4 acc0 = {0.f,0.f,0.f,0.f}, acc1 = {0.f,0.f,0.f,0.f};
    if (t > 0){
      // ---- tagged staging: load h_{t-1} (slot (t-1)&1), poll-by-tag ----
      const char* sT = hbT + ((size_t)(dl*2 + ((t-1)&1)) << 16);  // 4096 units * 16B
      u32 want = tagbase + (u32)t;   // tag of h_{t-1}
      i32x4 u[16];
      #pragma unroll
      for (int i=0;i<16;i++){ int g = i*256 + tid; u[i] = cload16(sT + ((size_t)g<<4)); }
      waitvm0();
      __builtin_amdgcn_sched_barrier(0);
      while (true){
        bool bad = false;
        #pragma unroll
        for (int i=0;i<16;i++) bad |= ((u32)u[i].z != want);
        if (!__any(bad)) break;
        __builtin_amdgcn_s_sleep(1);
        #pragma unroll
        for (int i=0;i<16;i++) if ((u32)u[i].z != want){ int g = i*256 + tid; u[i] = cload16(sT + ((size_t)g<<4)); }
        waitvm0();
        __builtin_amdgcn_sched_barrier(0);
      }
      __syncthreads();   // all waves' MFMA of t-1 done -> hA may be overwritten
      #pragma unroll
      for (int i=0;i<16;i++){
        int g = i*256 + tid; int b = g>>7, cu = g&127;
        u64 dat = ((u64)(u32)u[i].y << 32) | (u32)u[i].x;
        *(u64*)((char*)hA + b*1024 + ((((cu>>1) ^ (b&7)))<<4) + (cu&1)*8) = dat;
      }
      __syncthreads();   // hA ready
      #pragma unroll
      for (int kk=0; kk<16; kk++){
        int ch = (kk*4 + (lane>>4)) ^ (m0&7);
        bf16x8 a0 = *(const bf16x8*)(hA + m0*HH + ch*8);
        bf16x8 a1 = *(const bf16x8*)(hA + (m0+16)*HH + ch*8);
        acc0 = __builtin_amdgcn_mfma_f32_16x16x32_bf16(a0, bfr[kk], acc0, 0,0,0);
        acc1 = __builtin_amdgcn_mfma_f32_16x16x32_bf16(a1, bfr[kk], acc1, 0,0,0);
      }
    }
    // gates + cell update (gate exchange inside 16-lane groups via shfl_xor)
    #pragma unroll
    for (int mt=0; mt<2; mt++){
      #pragma unroll
      for (int rg=0; rg<4; rg++){
        float gpre = (mt ? acc1[rg] : acc0[rg]) + (float)gxr[mt][rg];
        float x4  = __shfl_xor(gpre, 4);
        float x8  = __shfl_xor(gpre, 8);
        float x12 = __shfl_xor(gpre, 12);
        float a04 = odd ? x4 : gpre,  b04 = odd ? gpre : x4;
        float a812 = odd ? x12 : x8,  b812 = odd ? x8 : x12;
        float ig = hi ? a812 : a04;
        float fg = hi ? b812 : b04;
        float gg = hi ? a04 : a812;
        float og = hi ? b04 : b812;
        float iv = sigmf(ig), fv = sigmf(fg), gv = tanhfast(gg), ov = sigmf(og);
        float c = cst[mt][rg]*fv + iv*gv;
        cst[mt][rg] = c;
        float hvv = ov * tanhfast(c);
        if (q == 0){
          int b = mt*16 + (lane>>4)*4 + rg;
          hP[w*128 + b*4 + hc] = __builtin_bit_cast(unsigned short, (bf16)hvv);
          if (layer == 1)   // full-precision output write
            __builtin_nontemporal_store(hvv,
              dout + ((size_t)(b*TT + tt))*(2*HH) + d*HH + s*16 + w*4 + hc);
          if (t == TT-1)
            hn[((size_t)((layer*2+d)*BB + b))*HH + s*16 + w*4 + hc] = hvv;
        }
      }
    }
    if (t == TT-1 && q == 0){
      #pragma unroll
      for (int mt=0; mt<2; mt++)
        #pragma unroll
        for (int rg=0; rg<4; rg++){
          int b = mt*16 + (lane>>4)*4 + rg;
          cn[((size_t)((layer*2+d)*BB + b))*HH + s*16 + w*4 + hc] = cst[mt][rg];
        }
    }
    // ---- per-wave publish: pack via tiny LDS, fire-and-forget tagged stores ----
    // (intra-wave only: hP[w] written by this wave's q==0 lanes, read by lanes<32)
    if (lane < 32){
      u64 d8 = *(const u64*)(hP + w*128 + lane*4);   // row=lane, 4 cols (compiler waits lgkm)
      if (t < TT-1){
        char* dT = hbT + ((size_t)(dl*2 + (t&1)) << 16);
        i32x4 unit;
        unit.x = (int)(u32)(d8 & 0xffffffffu);
        unit.y = (int)(u32)(d8 >> 32);
        unit.z = (int)(tagbase + (u32)t + 1u);
        unit.w = 0;
        cstore16(dT + ((size_t)(lane*128 + s*4 + w) << 4), unit);
      }
      if (layer == 0){
        int r = tt*BB + lane;
        int c = d*64 + s*2 + (w>>1);
        *(u64*)(out0 + (size_t)r*DIN + (size_t)(c ^ (r&7))*8 + (w&1)*4) = d8;
      }
    }
  }
}

extern "C" void kernel_launch(void* const* d_in, const int* in_sizes, int n_in,
                              void* d_out, int out_size, void* d_ws, size_t ws_size,
                              hipStream_t stream){
  const float* x  = (const float*)d_in[0];
  const float* Wx = (const float*)d_in[1];
  const float* bx = (const float*)d_in[2];
  const float* Wh = (const float*)d_in[3];
  const float* bh = (const float*)d_in[4];
  float* outp = (float*)d_out;
  char* ws = (char*)d_ws;

  const size_t szWxt  = (size_t)4*G4*DIN*2;   // 16.8 MB
  const size_t szWhb  = (size_t)4*G4*HH*2;    // 8.4 MB
  const size_t szBsum = (size_t)4*G4*4;
  const size_t szXO   = (size_t)MM*DIN*2;     // 33.6 MB
  const size_t szHbT  = (size_t)2*2*4096*16;  // 256 KB tagged h buffers

  // mode 0: f32 gx, both dirs, xo/out0 shared        (~327 MB)
  // mode 1: bf16 gx, both dirs, xo/out0 shared       (~193 MB)
  // mode 2: bf16 gx, one dir, separate out0, serial  (~160 MB)
  int mode = -1;
  size_t oWxt=0,oWhb=0,oBsum=0,oXO=0,oOut0=0,oHbT=0,oGx=0;
  for (int m=0; m<3 && mode<0; m++){
    size_t off = 0;
    auto take = [&](size_t b)->size_t{ size_t r = off; off = (off + b + 255) & ~(size_t)255; return r; };
    oWxt = take(szWxt); oWhb = take(szWhb); oBsum = take(szBsum);
    oXO  = take(szXO);
    oOut0 = (m==2) ? take(szXO) : oXO;
    oHbT = take(szHbT);
    size_t gxb = (m==0) ? (size_t)2*MM*G4*4 : (m==1) ? (size_t)2*MM*G4*2 : (size_t)MM*G4*2;
    oGx = take(gxb);
    if (off <= ws_size) mode = m;
  }
  if (mode < 0){
    k_dbg<<<1, 1, 0, stream>>>(outp, (float)((double)ws_size / 1048576.0));
    return;
  }

  bf16* Wxt  = (bf16*)(ws + oWxt);
  bf16* Whb  = (bf16*)(ws + oWhb);
  float* bsum= (float*)(ws + oBsum);
  bf16* xo   = (bf16*)(ws + oXO);
  bf16* out0 = (bf16*)(ws + oOut0);
  char* hbT  = ws + oHbT;
  void* gxp  = (void*)(ws + oGx);

  float* hn = outp + (size_t)BB*TT*2*HH;
  float* cn = hn + (size_t)4*BB*HH;

  hipMemsetAsync(hbT, 0, szHbT, stream);   // clean tags every launch (graph-safe)
  k_prep_bias<<<32, 256, 0, stream>>>(bx, bh, bsum);
  k_xswz<<<(MM*128)/256, 256, 0, stream>>>(x, xo);
  k_twx<<<dim3(16,32,4), 256, 0, stream>>>(Wx, Wxt);
  k_twh<<<dim3(8,32,4), 256, 0, stream>>>(Wh, Whb);

  if (mode == 0){
    float* gx = (float*)gxp;
    for (int layer=0; layer<2; layer++){
      k_gemm<float><<<dim3(16,128,2), 256, 0, stream>>>(xo, Wxt + (size_t)layer*2*G4*DIN,
                                                        bsum + layer*2*G4, gx);
      k_rec<float><<<64, 256, 0, stream>>>(Whb + (size_t)layer*2*G4*HH, gx, hbT,
                                           out0, outp, hn, cn, layer, 0);
    }
  } else if (mode == 1){
    bf16* gx = (bf16*)gxp;
    for (int layer=0; layer<2; layer++){
      k_gemm<bf16><<<dim3(16,128,2), 256, 0, stream>>>(xo, Wxt + (size_t)layer*2*G4*DIN,
                                                       bsum + layer*2*G4, gx);
      k_rec<bf16><<<64, 256, 0, stream>>>(Whb + (size_t)layer*2*G4*HH, gx, hbT,
                                          out0, outp, hn, cn, layer, 0);
    }
  } else {
    bf16* gx = (bf16*)gxp;
    for (int layer=0; layer<2; layer++){
      const bf16* A = layer ? out0 : xo;
      for (int dd=0; dd<2; dd++){
        k_gemm<bf16><<<dim3(16,128,1), 256, 0, stream>>>(A, Wxt + (size_t)(layer*2+dd)*G4*DIN,
                                                         bsum + (layer*2+dd)*G4, gx);
        k_rec<bf16><<<32, 256, 0, stream>>>(Whb + (size_t)layer*2*G4*HH, gx, hbT,
                                            out0, outp, hn, cn, layer, dd);
      }
    }
  }
}